// Round 9
// baseline (196.436 us; speedup 1.0000x reference)
//
#include <hip/hip_runtime.h>

// MinGRU stack: 3x (APL z/h + linear recurrence + maxabs-normalize) + APL out.
// B=8, T=2048, Din=D=Dout=64, P=16 knots on [-1,1].
// APL: direct L2 gather (one wave per sample, lane = output dim), per-lane
// precomputed (byte-offset, frac) shuffled in the inner loop, 4-deep batched.
// Chunk summary (pass1) fused into apl_dual via one end-of-block LDS compose.
// Fixup fused into pass2 (per-wave prefix compose of chunk summaries).
// Prep kernels kept separate (round-6 post-timing note).

#define WPB 16            // waves (samples) per apl block -> 1024 threads
#define CL  16            // chunk length == WPB (one block = one chunk)
#define NCB (2048 / CL)   // chunks per sequence = 128

// ---- table prep: combine (v[p], v[p+1]-v[p]) for z and h into one float4 ----
__global__ __launch_bounds__(256) void prep_dual_kernel(
    const float* __restrict__ vz, const float* __restrict__ vh,
    float4* __restrict__ tab)
{
    int idx = blockIdx.x * blockDim.x + threadIdx.x;   // over 64*15*64
    if (idx >= 64 * 15 * 64) return;
    int o = idx & 63;
    int p = (idx >> 6) % 15;
    int i = idx / (15 * 64);
    int base = (i * 16 + p) * 64 + o;
    float z0 = vz[base], z1 = vz[base + 64];
    float h0 = vh[base], h1 = vh[base + 64];
    tab[idx] = make_float4(z0, z1 - z0, h0, h1 - h0);
}

__global__ __launch_bounds__(256) void prep_out_kernel(
    const float* __restrict__ v, float2* __restrict__ tab)
{
    int idx = blockIdx.x * blockDim.x + threadIdx.x;
    if (idx >= 64 * 15 * 64) return;
    int o = idx & 63;
    int p = (idx >> 6) % 15;
    int i = idx / (15 * 64);
    int base = (i * 16 + p) * 64 + o;
    float v0 = v[base], v1 = v[base + 64];
    tab[idx] = make_float2(v0, v1 - v0);
}

// ---- APL (dual) + fused chunk summary ----
// One wave per sample; block = 16 consecutive samples = one scan chunk.
// Writes zh = (a, bb) = (1-z, z*hbar); wave 0 composes the 16 affine maps.
__global__ __launch_bounds__(1024) void apl_dual_kernel(
    const float* __restrict__ in, const float4* __restrict__ tab,
    float2* __restrict__ zh, float2* __restrict__ chunkAB)
{
    const int lane = threadIdx.x & 63;
    const int w = threadIdx.x >> 6;
    const int n = blockIdx.x * WPB + w;

    __shared__ float2 ab_lds[WPB][64];   // 8 KB

    float xv = in[(size_t)n * 64 + lane];
    float tv = fminf(fmaxf(xv, -1.f), 1.f) * 7.5f + 7.5f;   // [0,15]
    int iv = (int)tv; iv = iv > 14 ? 14 : iv;
    float frv = tv - (float)iv;
    int offv = lane * 15360 + (iv << 10);   // dim-l row byte offset

    const char* tb = (const char*)tab + lane * 16;
    float accz0 = 0.f, acch0 = 0.f, accz1 = 0.f, acch1 = 0.f;
#pragma unroll
    for (int i0 = 0; i0 < 64; i0 += 4) {
        int of0 = __shfl(offv, i0 + 0, 64);
        int of1 = __shfl(offv, i0 + 1, 64);
        int of2 = __shfl(offv, i0 + 2, 64);
        int of3 = __shfl(offv, i0 + 3, 64);
        float fr0 = __shfl(frv, i0 + 0, 64);
        float fr1 = __shfl(frv, i0 + 1, 64);
        float fr2 = __shfl(frv, i0 + 2, 64);
        float fr3 = __shfl(frv, i0 + 3, 64);
        float4 e0 = *(const float4*)(tb + of0);
        float4 e1 = *(const float4*)(tb + of1);
        float4 e2 = *(const float4*)(tb + of2);
        float4 e3 = *(const float4*)(tb + of3);
        accz0 += fmaf(fr0, e0.y, e0.x);
        acch0 += fmaf(fr0, e0.w, e0.z);
        accz1 += fmaf(fr1, e1.y, e1.x);
        acch1 += fmaf(fr1, e1.w, e1.z);
        accz0 += fmaf(fr2, e2.y, e2.x);
        acch0 += fmaf(fr2, e2.w, e2.z);
        accz1 += fmaf(fr3, e3.y, e3.x);
        acch1 += fmaf(fr3, e3.w, e3.z);
    }
    float accz = accz0 + accz1, acch = acch0 + acch1;
    float z = 1.f / (1.f + expf(-accz));
    float a = 1.f - z;
    float bb = z * acch;
    zh[(size_t)n * 64 + lane] = make_float2(a, bb);
    ab_lds[w][lane] = make_float2(a, bb);
    __syncthreads();

    if (w == 0) {   // compose chunk's 16 affine maps in time order
        float A = 1.f, Bc = 0.f;
#pragma unroll
        for (int k = 0; k < WPB; ++k) {
            float2 t = ab_lds[k][lane];
            A = t.x * A;
            Bc = fmaf(t.x, Bc, t.y);
        }
        chunkAB[(size_t)blockIdx.x * 64 + lane] = make_float2(A, Bc);
    }
}

// ---- APL (single table, output layer), 8-deep load batching ----
__global__ __launch_bounds__(1024) void apl_out_kernel(
    const float* __restrict__ in, const float2* __restrict__ tab,
    float* __restrict__ out)
{
    const int lane = threadIdx.x & 63;
    const int n = blockIdx.x * WPB + (threadIdx.x >> 6);

    float xv = in[(size_t)n * 64 + lane];
    float tv = fminf(fmaxf(xv, -1.f), 1.f) * 7.5f + 7.5f;
    int iv = (int)tv; iv = iv > 14 ? 14 : iv;
    float frv = tv - (float)iv;
    int offv = lane * 7680 + (iv << 9);

    const char* tb = (const char*)tab + lane * 8;
    float acc0 = 0.f, acc1 = 0.f;
#pragma unroll
    for (int i0 = 0; i0 < 64; i0 += 8) {
        int of[8]; float fr[8]; float2 e[8];
#pragma unroll
        for (int j = 0; j < 8; ++j) of[j] = __shfl(offv, i0 + j, 64);
#pragma unroll
        for (int j = 0; j < 8; ++j) fr[j] = __shfl(frv, i0 + j, 64);
#pragma unroll
        for (int j = 0; j < 8; ++j) e[j] = *(const float2*)(tb + of[j]);
#pragma unroll
        for (int j = 0; j < 8; j += 2) {
            acc0 += fmaf(fr[j], e[j].y, e[j].x);
            acc1 += fmaf(fr[j + 1], e[j + 1].y, e[j + 1].x);
        }
    }
    out[(size_t)n * 64 + lane] = acc0 + acc1;
}

// ---- pass2 (fused fixup): per-wave prefix compose, replay, normalize ----
// wave = one chunk of CL steps; chunk id wid in [0, B*NCB).
__global__ __launch_bounds__(256) void scan_pass2_kernel(
    const float2* __restrict__ zh, const float2* __restrict__ chunkAB,
    float* __restrict__ out, int T)
{
    const int lane = threadIdx.x & 63;
    const int wid = blockIdx.x * 4 + (threadIdx.x >> 6);
    const int b = wid / NCB, c = wid % NCB;

    // prefix: apply chunk summaries 0..c-1 to h0 = 0 (was scan_fixup)
    const float2* pc = chunkAB + ((size_t)b * NCB) * 64 + lane;
    float h = 0.f;
    int j = 0;
    for (; j + 8 <= c; j += 8) {
        float2 ab[8];
#pragma unroll
        for (int k = 0; k < 8; ++k) ab[k] = pc[(size_t)(j + k) * 64];
#pragma unroll
        for (int k = 0; k < 8; ++k) h = fmaf(ab[k].x, h, ab[k].y);
    }
    for (; j < c; ++j) { float2 ab = pc[(size_t)j * 64]; h = fmaf(ab.x, h, ab.y); }

    // replay this chunk with fused maxabs-normalize
    const float2* p = zh + ((size_t)b * T + (size_t)c * CL) * 64 + lane;
    float* o = out + ((size_t)b * T + (size_t)c * CL) * 64 + lane;
    for (int k0 = 0; k0 < CL; k0 += 8) {
        float2 v[8];
        float hs[8];
#pragma unroll
        for (int k = 0; k < 8; ++k) v[k] = p[(size_t)(k0 + k) * 64];
#pragma unroll
        for (int k = 0; k < 8; ++k) {
            h = fmaf(v[k].x, h, v[k].y);   // h = a*h + bb
            hs[k] = h;
        }
#pragma unroll
        for (int k = 0; k < 8; ++k) {
            float m = fabsf(hs[k]);
            m = fmaxf(m, __shfl_xor(m, 32, 64));
            m = fmaxf(m, __shfl_xor(m, 16, 64));
            m = fmaxf(m, __shfl_xor(m, 8, 64));
            m = fmaxf(m, __shfl_xor(m, 4, 64));
            m = fmaxf(m, __shfl_xor(m, 2, 64));
            m = fmaxf(m, __shfl_xor(m, 1, 64));
            o[(size_t)(k0 + k) * 64] = hs[k] / (m + 1e-6f);
        }
    }
}

extern "C" void kernel_launch(void* const* d_in, const int* in_sizes, int n_in,
                              void* d_out, int out_size, void* d_ws, size_t ws_size,
                              hipStream_t stream) {
    const float* x    = (const float*)d_in[0];
    const float* vz0  = (const float*)d_in[1];
    const float* vh0  = (const float*)d_in[2];
    const float* vz1  = (const float*)d_in[3];
    const float* vh1  = (const float*)d_in[4];
    const float* vz2  = (const float*)d_in[5];
    const float* vh2  = (const float*)d_in[6];
    const float* vout = (const float*)d_in[7];

    const int N = in_sizes[0] / 64;   // B*T = 16384
    const int T = 2048;
    const int B = N / T;              // 8

    char* ws = (char*)d_ws;
    const size_t TAB_ELEMS = (size_t)64 * 15 * 64;
    float2* zh      = (float2*)ws;                                  // 8 MB
    float*  cur     = (float*)(ws + 8388608);                       // 4 MB
    float4* tab0    = (float4*)(ws + 12582912);                     // 0.94 MB
    float4* tab1    = (float4*)(ws + 13565952);
    float4* tab2    = (float4*)(ws + 14548992);
    float2* tab_out = (float2*)(ws + 15532032);                     // 0.47 MB
    float2* chunkAB = (float2*)(ws + 16023552);                     // 1 MB region

    dim3 pblk(256), pgrd((TAB_ELEMS + 255) / 256);
    prep_dual_kernel<<<pgrd, pblk, 0, stream>>>(vz0, vh0, tab0);
    prep_dual_kernel<<<pgrd, pblk, 0, stream>>>(vz1, vh1, tab1);
    prep_dual_kernel<<<pgrd, pblk, 0, stream>>>(vz2, vh2, tab2);
    prep_out_kernel<<<pgrd, pblk, 0, stream>>>(vout, tab_out);

    dim3 ablk(64 * WPB), agrd(N / WPB);          // 1024 blocks of 1024 threads
    dim3 sblk(256), sgrd(B * NCB / 4);           // 256 blocks, wave = chunk

    const float4* tabs[3] = {tab0, tab1, tab2};
    const float* layer_in = x;
    for (int l = 0; l < 3; ++l) {
        apl_dual_kernel<<<agrd, ablk, 0, stream>>>(layer_in, tabs[l], zh, chunkAB);
        scan_pass2_kernel<<<sgrd, sblk, 0, stream>>>(zh, chunkAB, cur, T);
        layer_in = cur;
    }
    apl_out_kernel<<<agrd, ablk, 0, stream>>>(cur, tab_out, (float*)d_out);
}

// Round 11
// 186.101 us; speedup vs baseline: 1.0555x; 1.0555x over previous
//
#include <hip/hip_runtime.h>

// MinGRU stack: 3x (APL z/h + linear recurrence + maxabs-normalize) + APL out.
// B=8, T=2048, Din=D=Dout=64, P=16 knots on [-1,1].
// Structure = round 8 (best passing config, 192 us):
//   APL: direct L2 gather, one wave per sample, per-lane (offset, frac)
//   shuffled, 4-deep batched. Dual tables f32 float4 (bf16 z FAILED: relative
//   z error ~2e-3 is amplified ~21x/layer downstream -> 2.4 absmax).
//   Scan: separate pass1 / fixup / pass2 (fusing fixup into pass2 is
//   O(NCB^2) redundant reads -- round 9 regression).
// Only change vs round 8: OUTPUT table packed bf16x2 (feeds nothing
// downstream; +6e-3 error vs 0.27 budget), halving apl_out gather bytes.

#define WPB 8   // waves (samples) per block in APL kernels (512 threads)
#define NC 64   // chunks per sequence
#define CL 32   // timesteps per chunk (NC*CL == T == 2048)

__device__ __forceinline__ unsigned int pack_bf16(float f) {
    unsigned int u = __float_as_uint(f);
    return (u + 0x7fffu + ((u >> 16) & 1u)) >> 16;   // RNE
}

// ---- table prep: combine (v[p], v[p+1]-v[p]) for z and h into one float4 ----
__global__ __launch_bounds__(256) void prep_dual_kernel(
    const float* __restrict__ vz, const float* __restrict__ vh,
    float4* __restrict__ tab)
{
    int idx = blockIdx.x * blockDim.x + threadIdx.x;   // over 64*15*64
    if (idx >= 64 * 15 * 64) return;
    int o = idx & 63;
    int p = (idx >> 6) % 15;
    int i = idx / (15 * 64);
    int base = (i * 16 + p) * 64 + o;
    float z0 = vz[base], z1 = vz[base + 64];
    float h0 = vh[base], h1 = vh[base + 64];
    tab[idx] = make_float4(z0, z1 - z0, h0, h1 - h0);
}

// output table: packed bf16x2 (v0 low, dv high)
__global__ __launch_bounds__(256) void prep_out_kernel(
    const float* __restrict__ v, unsigned int* __restrict__ tab)
{
    int idx = blockIdx.x * blockDim.x + threadIdx.x;
    if (idx >= 64 * 15 * 64) return;
    int o = idx & 63;
    int p = (idx >> 6) % 15;
    int i = idx / (15 * 64);
    int base = (i * 16 + p) * 64 + o;
    float v0 = v[base], v1 = v[base + 64];
    tab[idx] = pack_bf16(v0) | (pack_bf16(v1 - v0) << 16);
}

// ---- APL (dual): z = sigmoid(apl_z), hbar = apl_h; one wave per sample ----
__global__ __launch_bounds__(512) void apl_dual_kernel(
    const float* __restrict__ in, const float4* __restrict__ tab,
    float2* __restrict__ zh, int N)
{
    const int lane = threadIdx.x & 63;
    const int n = blockIdx.x * WPB + (threadIdx.x >> 6);
    if (n >= N) return;

    float xv = in[(size_t)n * 64 + lane];
    float tv = fminf(fmaxf(xv, -1.f), 1.f) * 7.5f + 7.5f;   // [0,15]
    int iv = (int)tv; iv = iv > 14 ? 14 : iv;
    float frv = tv - (float)iv;
    int offv = lane * 15360 + (iv << 10);   // dim-l row byte offset

    const char* tb = (const char*)tab + lane * 16;
    float accz0 = 0.f, acch0 = 0.f, accz1 = 0.f, acch1 = 0.f;
#pragma unroll
    for (int i0 = 0; i0 < 64; i0 += 4) {
        int of0 = __shfl(offv, i0 + 0, 64);
        int of1 = __shfl(offv, i0 + 1, 64);
        int of2 = __shfl(offv, i0 + 2, 64);
        int of3 = __shfl(offv, i0 + 3, 64);
        float fr0 = __shfl(frv, i0 + 0, 64);
        float fr1 = __shfl(frv, i0 + 1, 64);
        float fr2 = __shfl(frv, i0 + 2, 64);
        float fr3 = __shfl(frv, i0 + 3, 64);
        float4 e0 = *(const float4*)(tb + of0);
        float4 e1 = *(const float4*)(tb + of1);
        float4 e2 = *(const float4*)(tb + of2);
        float4 e3 = *(const float4*)(tb + of3);
        accz0 += fmaf(fr0, e0.y, e0.x);
        acch0 += fmaf(fr0, e0.w, e0.z);
        accz1 += fmaf(fr1, e1.y, e1.x);
        acch1 += fmaf(fr1, e1.w, e1.z);
        accz0 += fmaf(fr2, e2.y, e2.x);
        acch0 += fmaf(fr2, e2.w, e2.z);
        accz1 += fmaf(fr3, e3.y, e3.x);
        acch1 += fmaf(fr3, e3.w, e3.z);
    }
    float accz = accz0 + accz1, acch = acch0 + acch1;
    float z = 1.f / (1.f + expf(-accz));
    zh[(size_t)n * 64 + lane] = make_float2(z, acch);
}

// ---- APL (bf16x2 table, output layer), 8-deep load batching ----
__global__ __launch_bounds__(512) void apl_out_kernel(
    const float* __restrict__ in, const unsigned int* __restrict__ tab,
    float* __restrict__ out, int N)
{
    const int lane = threadIdx.x & 63;
    const int n = blockIdx.x * WPB + (threadIdx.x >> 6);
    if (n >= N) return;

    float xv = in[(size_t)n * 64 + lane];
    float tv = fminf(fmaxf(xv, -1.f), 1.f) * 7.5f + 7.5f;
    int iv = (int)tv; iv = iv > 14 ? 14 : iv;
    float frv = tv - (float)iv;
    int offv = lane * 3840 + (iv << 8);   // uint rows: 256B; 15*256 per dim

    const char* tb = (const char*)tab + lane * 4;
    float acc0 = 0.f, acc1 = 0.f;
#pragma unroll
    for (int i0 = 0; i0 < 64; i0 += 8) {
        int of[8]; float fr[8]; unsigned int e[8];
#pragma unroll
        for (int j = 0; j < 8; ++j) of[j] = __shfl(offv, i0 + j, 64);
#pragma unroll
        for (int j = 0; j < 8; ++j) fr[j] = __shfl(frv, i0 + j, 64);
#pragma unroll
        for (int j = 0; j < 8; ++j) e[j] = *(const unsigned int*)(tb + of[j]);
#pragma unroll
        for (int j = 0; j < 8; j += 2) {
            acc0 += fmaf(fr[j], __uint_as_float(e[j] & 0xffff0000u),
                         __uint_as_float(e[j] << 16));
            acc1 += fmaf(fr[j + 1], __uint_as_float(e[j + 1] & 0xffff0000u),
                         __uint_as_float(e[j + 1] << 16));
        }
    }
    out[(size_t)n * 64 + lane] = acc0 + acc1;
}

// ---- scan pass 1: per-chunk affine summary (A, B): h_out = A*h_in + B ----
__global__ __launch_bounds__(256) void scan_pass1_kernel(
    const float2* __restrict__ zh, float2* __restrict__ chunkAB, int T)
{
    int lane = threadIdx.x & 63;
    int wid = blockIdx.x * (blockDim.x >> 6) + (threadIdx.x >> 6);  // b*NC + c
    int b = wid / NC, c = wid % NC;
    const float2* p = zh + ((size_t)b * T + (size_t)c * CL) * 64 + lane;

    float A = 1.f, Bc = 0.f;
    for (int k0 = 0; k0 < CL; k0 += 8) {
        float2 v[8];
#pragma unroll
        for (int k = 0; k < 8; ++k) v[k] = p[(size_t)(k0 + k) * 64];
#pragma unroll
        for (int k = 0; k < 8; ++k) {
            float a = 1.f - v[k].x;
            float bb = v[k].x * v[k].y;
            A *= a;
            Bc = fmaf(a, Bc, bb);
        }
    }
    chunkAB[(size_t)wid * 64 + lane] = make_float2(A, Bc);
}

// ---- scan fixup: sequential combine of NC chunk summaries per (b, d) ----
__global__ __launch_bounds__(64) void scan_fixup_kernel(
    const float2* __restrict__ chunkAB, float* __restrict__ hinit)
{
    int b = blockIdx.x;
    int d = threadIdx.x;
    const float2* p = chunkAB + (size_t)b * NC * 64 + d;
    float* o = hinit + (size_t)b * NC * 64 + d;

    float h = 0.f;  // h0 = 0
    for (int c0 = 0; c0 < NC; c0 += 8) {
        float2 ab[8];
#pragma unroll
        for (int k = 0; k < 8; ++k) ab[k] = p[(size_t)(c0 + k) * 64];
#pragma unroll
        for (int k = 0; k < 8; ++k) {
            o[(size_t)(c0 + k) * 64] = h;
            h = fmaf(ab[k].x, h, ab[k].y);
        }
    }
}

// ---- scan pass 2: replay chunk from hinit, fused maxabs-normalize ----
__global__ __launch_bounds__(256) void scan_pass2_kernel(
    const float2* __restrict__ zh, const float* __restrict__ hinit,
    float* __restrict__ out, int T)
{
    int lane = threadIdx.x & 63;
    int wid = blockIdx.x * (blockDim.x >> 6) + (threadIdx.x >> 6);  // b*NC + c
    int b = wid / NC, c = wid % NC;
    const float2* p = zh + ((size_t)b * T + (size_t)c * CL) * 64 + lane;
    float* o = out + ((size_t)b * T + (size_t)c * CL) * 64 + lane;

    float h = hinit[(size_t)wid * 64 + lane];
    for (int k0 = 0; k0 < CL; k0 += 8) {
        float2 v[8];
        float hs[8];
#pragma unroll
        for (int k = 0; k < 8; ++k) v[k] = p[(size_t)(k0 + k) * 64];
#pragma unroll
        for (int k = 0; k < 8; ++k) {
            h = fmaf(v[k].x, v[k].y - h, h);   // h += z*(hbar - h)
            hs[k] = h;
        }
#pragma unroll
        for (int k = 0; k < 8; ++k) {
            float m = fabsf(hs[k]);
            m = fmaxf(m, __shfl_xor(m, 32, 64));
            m = fmaxf(m, __shfl_xor(m, 16, 64));
            m = fmaxf(m, __shfl_xor(m, 8, 64));
            m = fmaxf(m, __shfl_xor(m, 4, 64));
            m = fmaxf(m, __shfl_xor(m, 2, 64));
            m = fmaxf(m, __shfl_xor(m, 1, 64));
            o[(size_t)(k0 + k) * 64] = hs[k] / (m + 1e-6f);
        }
    }
}

extern "C" void kernel_launch(void* const* d_in, const int* in_sizes, int n_in,
                              void* d_out, int out_size, void* d_ws, size_t ws_size,
                              hipStream_t stream) {
    const float* x    = (const float*)d_in[0];
    const float* vz0  = (const float*)d_in[1];
    const float* vh0  = (const float*)d_in[2];
    const float* vz1  = (const float*)d_in[3];
    const float* vh1  = (const float*)d_in[4];
    const float* vz2  = (const float*)d_in[5];
    const float* vh2  = (const float*)d_in[6];
    const float* vout = (const float*)d_in[7];

    const int N = in_sizes[0] / 64;   // B*T = 16384
    const int T = NC * CL;            // 2048
    const int B = N / T;              // 8

    char* ws = (char*)d_ws;
    const size_t TAB_ELEMS = (size_t)64 * 15 * 64;
    float2* zh      = (float2*)ws;                                  // 8 MB
    float*  cur     = (float*)(ws + 8388608);                       // 4 MB
    float4* tab0    = (float4*)(ws + 12582912);                     // 0.94 MB
    float4* tab1    = (float4*)(ws + 13565952);
    float4* tab2    = (float4*)(ws + 14548992);
    unsigned int* tab_out = (unsigned int*)(ws + 15532032);         // 240 KB
    float2* chunkAB = (float2*)(ws + 16023552);                     // 256 KB
    float*  hinit   = (float*)(ws + 16285696);                      // 128 KB

    dim3 pblk(256), pgrd((TAB_ELEMS + 255) / 256);
    prep_dual_kernel<<<pgrd, pblk, 0, stream>>>(vz0, vh0, tab0);
    prep_dual_kernel<<<pgrd, pblk, 0, stream>>>(vz1, vh1, tab1);
    prep_dual_kernel<<<pgrd, pblk, 0, stream>>>(vz2, vh2, tab2);
    prep_out_kernel<<<pgrd, pblk, 0, stream>>>(vout, tab_out);

    dim3 ablk(64 * WPB), agrd((N + WPB - 1) / WPB);
    dim3 sblk(256), sgrd(B * NC / 4);   // 4 waves (chunks) per block

    const float4* tabs[3] = {tab0, tab1, tab2};
    const float* layer_in = x;
    for (int l = 0; l < 3; ++l) {
        apl_dual_kernel<<<agrd, ablk, 0, stream>>>(layer_in, tabs[l], zh, N);
        scan_pass1_kernel<<<sgrd, sblk, 0, stream>>>(zh, chunkAB, T);
        scan_fixup_kernel<<<B, 64, 0, stream>>>(chunkAB, hinit);
        scan_pass2_kernel<<<sgrd, sblk, 0, stream>>>(zh, hinit, cur, T);
        layer_in = cur;
    }
    apl_out_kernel<<<agrd, ablk, 0, stream>>>(cur, tab_out, (float*)d_out, N);
}